// Round 9
// baseline (516.011 us; speedup 1.0000x reference)
//
#include <hip/hip_runtime.h>
#include <math.h>

typedef __attribute__((ext_vector_type(8))) short short8;
typedef __attribute__((ext_vector_type(4))) float f32x4;
typedef __attribute__((ext_vector_type(2))) float f32x2;

#define LRELU(x) ((x) > 0.0f ? (x) : 0.01f * (x))

__device__ __forceinline__ float bf2f(unsigned short h) {
    return __uint_as_float(((unsigned int)h) << 16);
}
__device__ __forceinline__ unsigned short f2bf(float f) {
    unsigned int u = __float_as_uint(f);
    return (unsigned short)((u + 0x7FFFu + ((u >> 16) & 1u)) >> 16);
}
// round-half-up bf16 pair pack: ~5 VALU vs ~10 for RNE; <=0.5 ULP error
__device__ __forceinline__ unsigned int pack_bf16_pair(float lo, float hi) {
    unsigned int ul = __float_as_uint(lo) + 0x8000u;
    unsigned int uh = __float_as_uint(hi) + 0x8000u;
    return (ul >> 16) | (uh & 0xFFFF0000u);
}
__device__ __forceinline__ float2 stats_from(const float* sums, int b, float count) {
    float s = sums[2 * b], q = sums[2 * b + 1];
    float mean = s / count;
    float var = (q - s * s / count) / (count - 1.0f);  // ddof=1
    var = fmaxf(var, 0.0f);
    return make_float2(mean, 1.0f / (sqrtf(var) + 1e-5f));
}
// init pattern 0xFFFFFFFF (-NaN): positives via signed max, negatives via unsigned min
__device__ __forceinline__ void atomicMaxF(float* a, float v) {
    if (v >= 0.0f) atomicMax((int*)a, __float_as_int(v));
    else           atomicMin((unsigned int*)a, __float_as_uint(v));
}
// y = lrelu(x * a + c) on a packed bf16 pair, via packed-f32 (VOP3P) ops
__device__ __forceinline__ unsigned int norm_pair(unsigned int u, float a, float c) {
    f32x2 v;
    v.x = __uint_as_float(u << 16);          // lo bf16 -> f32 (1 inst)
    v.y = __uint_as_float(u & 0xFFFF0000u);  // hi bf16 -> f32 (1 inst)
    v = v * a + c;                           // v_pk_fma_f32
    f32x2 m = v * 0.01f;                     // v_pk_mul_f32
    v = __builtin_elementwise_max(v, m);     // v_pk_max_f32
    return pack_bf16_pair(v.x, v.y);
}
__device__ __forceinline__ uint4 norm8(uint4 v, float a, float c) {
    v.x = norm_pair(v.x, a, c); v.y = norm_pair(v.y, a, c);
    v.z = norm_pair(v.z, a, c); v.w = norm_pair(v.w, a, c);
    return v;
}

// w [O][Cin][3] f32  ->  wq [O][3*Cin] bf16 with k' = j*Cin + c
__global__ void prep_weights(const float* __restrict__ w, unsigned short* __restrict__ wq,
                             int O, int Cin)
{
    const int K = 3 * Cin, total = O * K;
    for (int i = blockIdx.x * blockDim.x + threadIdx.x; i < total;
         i += gridDim.x * blockDim.x) {
        int o = i / K, kp = i - o * K;
        int j = kp / Cin, c = kp - j * Cin;
        wq[i] = f2bf(w[(o * Cin + c) * 3 + j]);   // RNE for weights (cost negligible)
    }
}

// data [128][64][1024] f32 -> xT [nB][1024][64] bf16 (tower select on b>=128)
__global__ __launch_bounds__(256) void transpose_in(const float* __restrict__ inA,
                                                    const float* __restrict__ inB,
                                                    unsigned short* __restrict__ xT)
{
    const int b = blockIdx.y, n0 = blockIdx.x * 64;
    const float* in = (b >= 128 ? inB : inA) + ((size_t)(b & 127) * 64) * 1024;
    const int tid = threadIdx.x;
    __shared__ float tile[64][65];
    const int nn = tid & 63, cw = tid >> 6;
#pragma unroll
    for (int i = 0; i < 16; i++) {
        int c = i * 4 + cw;
        tile[c][nn] = in[(size_t)c * 1024 + n0 + nn];
    }
    __syncthreads();
    const int n = tid >> 2, cp = (tid & 3) * 16;
    unsigned int pk[8];
#pragma unroll
    for (int i = 0; i < 8; i++) {
        unsigned short lo = f2bf(tile[cp + 2 * i][n]);   // RNE for input data
        unsigned short hi = f2bf(tile[cp + 2 * i + 1][n]);
        pk[i] = (unsigned int)lo | ((unsigned int)hi << 16);
    }
    unsigned short* dst = xT + ((size_t)b * 1024 + n0 + n) * 64 + cp;
    uint4 v0 = {pk[0], pk[1], pk[2], pk[3]};
    uint4 v1 = {pk[4], pk[5], pk[6], pk[7]};
    *(uint4*)dst = v0;
    *(uint4*)(dst + 8) = v1;
}

// MFMA gather-conv, register-staged pipelined K-loop (named scalar uint4 staging
// -- local arrays fail SROA and go to scratch: the R5-R7 600MB/dispatch bug).
// NORM: y = lrelu((x-mean)*inv) applied in registers during staging.
template <int BM, bool POOL, bool NORM>
__global__ __launch_bounds__(256, 4) void conv_mfma(
    const unsigned short* __restrict__ xT,   // [nB][1024][Cin] bf16 (raw, pre-norm)
    const int* __restrict__ idxA,            // [128][3069]
    const int* __restrict__ idxB,
    const unsigned short* __restrict__ wq,   // [O][K] bf16 (k'=j*Cin+c)
    const float* __restrict__ bias,          // [O] f32
    unsigned short* __restrict__ out,        // [nB][1024][O] bf16 (unused if POOL)
    float* __restrict__ sums,                // [nB][2] accum (this layer's raw stats)
    float* __restrict__ pmax,                // [nB][64] (POOL only)
    const float* __restrict__ normSums,      // [nB][2] prev-layer stats (NORM only)
    float normCount, int Cin, int cinShift, int O, int K)
{
    constexpr int WM = BM / 2, MT = WM / 16;
    constexpr int NW = (BM == 128) ? 4 : 2;      // 16B packets of wt per thread
    const int b   = blockIdx.x;
    const int o0  = blockIdx.y * BM;
    const int nt0 = blockIdx.z << 7;
    const int tid = threadIdx.x;
    const int lane = tid & 63, wave = tid >> 6;
    const int wo = wave & 1, wn = wave >> 1;
    const int quad = lane >> 4, l15 = lane & 15;
    const int blkid = lane & 7;

    __shared__ __align__(16) unsigned short wt[BM * 64];
    __shared__ __align__(16) unsigned short gt[128 * 64];

    f32x4 acc[MT][4];
#pragma unroll
    for (int i = 0; i < MT; i++)
#pragma unroll
        for (int t = 0; t < 4; t++) acc[i][t] = (f32x4){0.f, 0.f, 0.f, 0.f};

    const unsigned short* xTb = xT + (((size_t)b) << 10) * (size_t)Cin;
    const int* idxb = (b >= 128 ? idxB : idxA) + (size_t)(b & 127) * 3069;

    float na = 1.0f, nc = 0.0f;
    if (NORM) {
        float2 st = stats_from(normSums, b, normCount);
        na = st.y; nc = -st.x * st.y;
    }

    // --- staging mapping ---
    const int gr = tid >> 1, gh = tid & 1;       // gt row (n), 32-elem half
    int s0, s1, s2;
    {
        int n = nt0 + gr;
        int t0 = (n == 0) ? 0 : (n - 1);         // n==0 row is garbage, zeroed later
        s0 = idxb[3 * t0]; s1 = idxb[3 * t0 + 1]; s2 = idxb[3 * t0 + 2];
    }
    const int wr   = (BM == 128) ? (tid >> 1) : (tid >> 2);  // wt row (o)
    const int wseg = (BM == 128) ? (tid & 1) : (tid & 3);    // segment of NW packets
    const unsigned short* wrow = wq + (size_t)(o0 + wr) * K + wseg * (NW * 8);
    const int gswz = gr & 7, wswz = wr & 7;

    uint4 g0, g1, g2, g3, w0, w1, w2, w3;

#define LOADC(KC) {                                                              \
        const int k64_ = (KC) << 6;                                              \
        const int j_   = k64_ >> cinShift;                                       \
        const int c0_  = k64_ & (Cin - 1);                                       \
        const int src_ = (j_ == 0) ? s0 : ((j_ == 1) ? s1 : s2);                 \
        const uint4* gp_ = (const uint4*)(xTb + (size_t)src_ * Cin + c0_ + gh * 32); \
        g0 = gp_[0]; g1 = gp_[1]; g2 = gp_[2]; g3 = gp_[3];                      \
        const uint4* wp_ = (const uint4*)(wrow + k64_);                          \
        w0 = wp_[0]; w1 = wp_[1];                                                \
        if (NW == 4) { w2 = wp_[2]; w3 = wp_[3]; }                               \
    }

#define STAGE() {                                                                \
        uint4 h0 = g0, h1 = g1, h2 = g2, h3 = g3;                                \
        if (NORM) {                                                              \
            h0 = norm8(h0, na, nc); h1 = norm8(h1, na, nc);                      \
            h2 = norm8(h2, na, nc); h3 = norm8(h3, na, nc);                      \
        }                                                                        \
        *(uint4*)&gt[gr * 64 + (((gh << 2) | 0) ^ gswz) * 8] = h0;               \
        *(uint4*)&gt[gr * 64 + (((gh << 2) | 1) ^ gswz) * 8] = h1;               \
        *(uint4*)&gt[gr * 64 + (((gh << 2) | 2) ^ gswz) * 8] = h2;               \
        *(uint4*)&gt[gr * 64 + (((gh << 2) | 3) ^ gswz) * 8] = h3;               \
        *(uint4*)&wt[wr * 64 + ((wseg * NW + 0) ^ wswz) * 8] = w0;               \
        *(uint4*)&wt[wr * 64 + ((wseg * NW + 1) ^ wswz) * 8] = w1;               \
        if (NW == 4) {                                                           \
            *(uint4*)&wt[wr * 64 + ((wseg * NW + 2) ^ wswz) * 8] = w2;           \
            *(uint4*)&wt[wr * 64 + ((wseg * NW + 3) ^ wswz) * 8] = w3;           \
        }                                                                        \
    }

    const int nChunks = K >> 6;
    LOADC(0);
    for (int kc = 0; kc < nChunks; ++kc) {
        if (kc) __syncthreads();        // prior chunk's readers done
        STAGE();                        // waits in-flight loads, writes LDS
        if (kc + 1 < nChunks) LOADC(kc + 1);  // prefetch stays in flight past barrier
        __syncthreads();                // staged data visible
#pragma unroll
        for (int st = 0; st < 2; ++st) {
            short8 af[MT], bfv[4];
            const int qb = st * 4 + quad;
#pragma unroll
            for (int i = 0; i < MT; i++) {
                const int orow = wo * WM + i * 16 + l15;
                af[i] = *(const short8*)&wt[orow * 64 + ((qb ^ blkid) << 3)];
            }
#pragma unroll
            for (int t = 0; t < 4; t++) {
                const int nrow = wn * 64 + t * 16 + l15;
                bfv[t] = *(const short8*)&gt[nrow * 64 + ((qb ^ blkid) << 3)];
            }
#pragma unroll
            for (int i = 0; i < MT; i++)
#pragma unroll
                for (int t = 0; t < 4; t++)
                    acc[i][t] = __builtin_amdgcn_mfma_f32_16x16x32_bf16(
                        af[i], bfv[t], acc[i][t], 0, 0, 0);
        }
    }
#undef LOADC
#undef STAGE

    // epilogue: bias, zero col 0, store (unless POOL), fused stats, fused max-pool
    float lsum = 0.f, lsq = 0.f;
#pragma unroll
    for (int i = 0; i < MT; i++) {
        const int ob = o0 + wo * WM + i * 16 + quad * 4;
        const float4 bv = *(const float4*)(bias + ob);
        float mx0 = -1e30f, mx1 = -1e30f, mx2 = -1e30f, mx3 = -1e30f;
#pragma unroll
        for (int t = 0; t < 4; t++) {
            const int n = nt0 + wn * 64 + t * 16 + l15;
            float v0 = acc[i][t][0] + bv.x;
            float v1 = acc[i][t][1] + bv.y;
            float v2 = acc[i][t][2] + bv.z;
            float v3 = acc[i][t][3] + bv.w;
            if (n == 0) { v0 = v1 = v2 = v3 = 0.f; }
            lsum += v0 + v1 + v2 + v3;
            lsq  += v0 * v0 + v1 * v1 + v2 * v2 + v3 * v3;
            if (POOL) {
                mx0 = fmaxf(mx0, v0); mx1 = fmaxf(mx1, v1);
                mx2 = fmaxf(mx2, v2); mx3 = fmaxf(mx3, v3);
            } else {
                uint2 pk;
                pk.x = pack_bf16_pair(v0, v1);
                pk.y = pack_bf16_pair(v2, v3);
                *(uint2*)&out[((size_t)b * 1024 + n) * O + ob] = pk;
            }
        }
        if (POOL) {
#pragma unroll
            for (int off = 1; off < 16; off <<= 1) {
                mx0 = fmaxf(mx0, __shfl_xor(mx0, off));
                mx1 = fmaxf(mx1, __shfl_xor(mx1, off));
                mx2 = fmaxf(mx2, __shfl_xor(mx2, off));
                mx3 = fmaxf(mx3, __shfl_xor(mx3, off));
            }
            if (l15 == 0) {
                atomicMaxF(&pmax[(size_t)b * 64 + ob + 0], mx0);
                atomicMaxF(&pmax[(size_t)b * 64 + ob + 1], mx1);
                atomicMaxF(&pmax[(size_t)b * 64 + ob + 2], mx2);
                atomicMaxF(&pmax[(size_t)b * 64 + ob + 3], mx3);
            }
        }
    }
#pragma unroll
    for (int off = 32; off > 0; off >>= 1) {
        lsum += __shfl_down(lsum, off);
        lsq  += __shfl_down(lsq, off);
    }
    float* red = (float*)wt;  // wt dead after K-loop
    if (lane == 0) { red[wave] = lsum; red[4 + wave] = lsq; }
    __syncthreads();
    if (tid == 0) {
        atomicAdd(&sums[2 * b + 0], red[0] + red[1] + red[2] + red[3]);
        atomicAdd(&sums[2 * b + 1], red[4] + red[5] + red[6] + red[7]);
    }
}

// pooled max -> normalize -> fc1+lrelu -> fc2
__global__ __launch_bounds__(64) void fc_head(
    const float* __restrict__ pmax, const float* __restrict__ sums3, float count,
    const float* __restrict__ w_fc1, const float* __restrict__ b_fc1,
    const float* __restrict__ w_fc2, const float* __restrict__ b_fc2,
    float* __restrict__ y)
{
    const int b = blockIdx.x, t = threadIdx.x;
    __shared__ float pooled[64];
    __shared__ float hid[32];
    float2 s = stats_from(sums3, b, count);
    pooled[t] = (pmax[(size_t)b * 64 + t] - s.x) * s.y;
    __syncthreads();
    if (t < 32) {
        float h = b_fc1[t];
#pragma unroll
        for (int c = 0; c < 64; c++) h += pooled[c] * w_fc1[t * 64 + c];
        hid[t] = LRELU(h);
    }
    __syncthreads();
    if (t == 0) {
        float v = b_fc2[0];
#pragma unroll
        for (int c = 0; c < 32; c++) v += hid[c] * w_fc2[c];
        y[b] = v;
    }
}

__global__ void sigmoid_diff(const float* __restrict__ y1,
                             const float* __restrict__ y2,
                             float* __restrict__ out)
{
    int b = threadIdx.x;
    if (b < 128) out[b] = 1.0f / (1.0f + expf(-(y1[b] - y2[b])));
}

extern "C" void kernel_launch(void* const* d_in, const int* in_sizes, int n_in,
                              void* d_out, int out_size, void* d_ws, size_t ws_size,
                              hipStream_t stream)
{
    const float* data1 = (const float*)d_in[0];
    const int*   idx1  = (const int*)d_in[1];
    const float* data2 = (const float*)d_in[2];
    const int*   idx2  = (const int*)d_in[3];
    const float* w1 = (const float*)d_in[4];
    const float* b1 = (const float*)d_in[5];
    const float* w2 = (const float*)d_in[6];
    const float* b2 = (const float*)d_in[7];
    const float* w3 = (const float*)d_in[8];
    const float* b3 = (const float*)d_in[9];
    const float* wfc1 = (const float*)d_in[10];
    const float* bfc1 = (const float*)d_in[11];
    const float* wfc2 = (const float*)d_in[12];
    const float* bfc2 = (const float*)d_in[13];

    const size_t needM = (size_t)256 * 1024 * (64 + 256 + 128) * 2 + 768 * 1024;
    const bool merged = ws_size >= needM;
    const int nB = merged ? 256 : 128;
    const size_t szXT = (size_t)nB * 1024 * 64 * 2;
    const size_t szA1 = (size_t)nB * 1024 * 256 * 2;
    const size_t szA2 = (size_t)nB * 1024 * 128 * 2;

    char* ws = (char*)d_ws;
    unsigned short* xT = (unsigned short*)ws;
    unsigned short* a1 = (unsigned short*)(ws + szXT);
    unsigned short* a2 = (unsigned short*)(ws + szXT + szA1);
    char* tail = ws + szXT + szA1 + szA2;
    unsigned short* wq1 = (unsigned short*)tail;                 // 96 KB
    unsigned short* wq2 = (unsigned short*)(tail + 128 * 1024);  // 192 KB
    unsigned short* wq3 = (unsigned short*)(tail + 384 * 1024);  // 48 KB
    float* sums = (float*)(tail + 448 * 1024);                   // 3*nB*2 f32
    float* pmax = (float*)(tail + 512 * 1024);                   // nB*64 f32
    float* yv   = (float*)(tail + 640 * 1024);                   // 256 f32

    prep_weights<<<96, 256, 0, stream>>>(w1, wq1, 256, 64);
    prep_weights<<<96, 256, 0, stream>>>(w2, wq2, 128, 256);
    prep_weights<<<96, 256, 0, stream>>>(w3, wq3, 64, 128);

    const int nIter = merged ? 1 : 2;
    for (int t = 0; t < nIter; ++t) {
        const float* dA = (merged || t == 0) ? data1 : data2;
        const float* dB = merged ? data2 : dA;
        const int* iA = (merged || t == 0) ? idx1 : idx2;
        const int* iB = merged ? idx2 : iA;
        float* s1 = sums;
        float* s2 = sums + nB * 2;
        float* s3 = sums + nB * 4;

        hipMemsetAsync(sums, 0, 3 * (size_t)nB * 2 * sizeof(float), stream);
        hipMemsetAsync(pmax, 0xFF, (size_t)nB * 64 * sizeof(float), stream);

        transpose_in<<<dim3(16, nB), 256, 0, stream>>>(dA, dB, xT);

        conv_mfma<128, false, false><<<dim3(nB, 2, 8), 256, 0, stream>>>(
            xT, iA, iB, wq1, b1, a1, s1, nullptr, nullptr, 0.0f, 64, 6, 256, 192);

        conv_mfma<128, false, true><<<dim3(nB, 1, 8), 256, 0, stream>>>(
            a1, iA, iB, wq2, b2, a2, s2, nullptr, s1, 256.0f * 1024.0f, 256, 8, 128, 768);

        conv_mfma<64, true, true><<<dim3(nB, 1, 8), 256, 0, stream>>>(
            a2, iA, iB, wq3, b3, nullptr, s3, pmax, s2, 128.0f * 1024.0f, 128, 7, 64, 384);

        fc_head<<<nB, 64, 0, stream>>>(pmax, s3, 64.0f * 1024.0f,
                                       wfc1, bfc1, wfc2, bfc2,
                                       yv + (merged ? 0 : t * 128));
    }
    sigmoid_diff<<<1, 128, 0, stream>>>(yv, yv + 128, (float*)d_out);
}

// Round 10
// 347.447 us; speedup vs baseline: 1.4852x; 1.4852x over previous
//
#include <hip/hip_runtime.h>
#include <math.h>

typedef __attribute__((ext_vector_type(8))) short short8;
typedef __attribute__((ext_vector_type(4))) float f32x4;
typedef __attribute__((ext_vector_type(2))) float f32x2;

#define LRELU(x) ((x) > 0.0f ? (x) : 0.01f * (x))

__device__ __forceinline__ float bf2f(unsigned short h) {
    return __uint_as_float(((unsigned int)h) << 16);
}
__device__ __forceinline__ unsigned short f2bf(float f) {
    unsigned int u = __float_as_uint(f);
    return (unsigned short)((u + 0x7FFFu + ((u >> 16) & 1u)) >> 16);
}
// round-half-up bf16 pair pack: ~5 VALU vs ~10 for RNE; <=0.5 ULP error
__device__ __forceinline__ unsigned int pack_bf16_pair(float lo, float hi) {
    unsigned int ul = __float_as_uint(lo) + 0x8000u;
    unsigned int uh = __float_as_uint(hi) + 0x8000u;
    return (ul >> 16) | (uh & 0xFFFF0000u);
}
__device__ __forceinline__ float2 stats_from(const float* sums, int b, float count) {
    float s = sums[2 * b], q = sums[2 * b + 1];
    float mean = s / count;
    float var = (q - s * s / count) / (count - 1.0f);  // ddof=1
    var = fmaxf(var, 0.0f);
    return make_float2(mean, 1.0f / (sqrtf(var) + 1e-5f));
}
// init pattern 0xFFFFFFFF (-NaN): positives via signed max, negatives via unsigned min
__device__ __forceinline__ void atomicMaxF(float* a, float v) {
    if (v >= 0.0f) atomicMax((int*)a, __float_as_int(v));
    else           atomicMin((unsigned int*)a, __float_as_uint(v));
}
// y = lrelu(x * a + c) on a packed bf16 pair, via packed-f32 (VOP3P) ops
__device__ __forceinline__ unsigned int norm_pair(unsigned int u, float a, float c) {
    f32x2 v;
    v.x = __uint_as_float(u << 16);          // lo bf16 -> f32 (1 inst)
    v.y = __uint_as_float(u & 0xFFFF0000u);  // hi bf16 -> f32 (1 inst)
    v = v * a + c;                           // v_pk_fma_f32
    f32x2 m = v * 0.01f;                     // v_pk_mul_f32
    v = __builtin_elementwise_max(v, m);     // v_pk_max_f32
    return pack_bf16_pair(v.x, v.y);
}
__device__ __forceinline__ uint4 norm8(uint4 v, float a, float c) {
    v.x = norm_pair(v.x, a, c); v.y = norm_pair(v.y, a, c);
    v.z = norm_pair(v.z, a, c); v.w = norm_pair(v.w, a, c);
    return v;
}

// w [O][Cin][3] f32  ->  wq [O][3*Cin] bf16 with k' = j*Cin + c
__global__ void prep_weights(const float* __restrict__ w, unsigned short* __restrict__ wq,
                             int O, int Cin)
{
    const int K = 3 * Cin, total = O * K;
    for (int i = blockIdx.x * blockDim.x + threadIdx.x; i < total;
         i += gridDim.x * blockDim.x) {
        int o = i / K, kp = i - o * K;
        int j = kp / Cin, c = kp - j * Cin;
        wq[i] = f2bf(w[(o * Cin + c) * 3 + j]);   // RNE for weights (cost negligible)
    }
}

// data [128][64][1024] f32 -> xT [nB][1024][64] bf16 (tower select on b>=128)
__global__ __launch_bounds__(256) void transpose_in(const float* __restrict__ inA,
                                                    const float* __restrict__ inB,
                                                    unsigned short* __restrict__ xT)
{
    const int b = blockIdx.y, n0 = blockIdx.x * 64;
    const float* in = (b >= 128 ? inB : inA) + ((size_t)(b & 127) * 64) * 1024;
    const int tid = threadIdx.x;
    __shared__ float tile[64][65];
    const int nn = tid & 63, cw = tid >> 6;
#pragma unroll
    for (int i = 0; i < 16; i++) {
        int c = i * 4 + cw;
        tile[c][nn] = in[(size_t)c * 1024 + n0 + nn];
    }
    __syncthreads();
    const int n = tid >> 2, cp = (tid & 3) * 16;
    unsigned int pk[8];
#pragma unroll
    for (int i = 0; i < 8; i++) {
        unsigned short lo = f2bf(tile[cp + 2 * i][n]);   // RNE for input data
        unsigned short hi = f2bf(tile[cp + 2 * i + 1][n]);
        pk[i] = (unsigned int)lo | ((unsigned int)hi << 16);
    }
    unsigned short* dst = xT + ((size_t)b * 1024 + n0 + n) * 64 + cp;
    uint4 v0 = {pk[0], pk[1], pk[2], pk[3]};
    uint4 v1 = {pk[4], pk[5], pk[6], pk[7]};
    *(uint4*)dst = v0;
    *(uint4*)(dst + 8) = v1;
}

// MFMA gather-conv, register-staged pipelined K-loop (named scalar uint4 staging
// -- local arrays fail SROA and go to scratch: the R5-R7 600MB/dispatch bug).
// NORM: y = lrelu((x-mean)*inv) applied in registers during staging.
// __launch_bounds__(256, 2) EXACTLY: at (256,4) the allocator targets 64 VGPR and
// spills the staging scalars (R9: 430 MB scratch traffic, 2x regression). Do not raise.
template <int BM, bool POOL, bool NORM>
__global__ __launch_bounds__(256, 2) void conv_mfma(
    const unsigned short* __restrict__ xT,   // [nB][1024][Cin] bf16 (raw, pre-norm)
    const int* __restrict__ idxA,            // [128][3069]
    const int* __restrict__ idxB,
    const unsigned short* __restrict__ wq,   // [O][K] bf16 (k'=j*Cin+c)
    const float* __restrict__ bias,          // [O] f32
    unsigned short* __restrict__ out,        // [nB][1024][O] bf16 (unused if POOL)
    float* __restrict__ sums,                // [nB][2] accum (this layer's raw stats)
    float* __restrict__ pmax,                // [nB][64] (POOL only)
    const float* __restrict__ normSums,      // [nB][2] prev-layer stats (NORM only)
    float normCount, int Cin, int cinShift, int O, int K)
{
    constexpr int WM = BM / 2, MT = WM / 16;
    constexpr int NW = (BM == 128) ? 4 : 2;      // 16B packets of wt per thread
    const int b   = blockIdx.x;
    const int o0  = blockIdx.y * BM;
    const int nt0 = blockIdx.z << 7;
    const int tid = threadIdx.x;
    const int lane = tid & 63, wave = tid >> 6;
    const int wo = wave & 1, wn = wave >> 1;
    const int quad = lane >> 4, l15 = lane & 15;
    const int blkid = lane & 7;

    __shared__ __align__(16) unsigned short wt[BM * 64];
    __shared__ __align__(16) unsigned short gt[128 * 64];

    f32x4 acc[MT][4];
#pragma unroll
    for (int i = 0; i < MT; i++)
#pragma unroll
        for (int t = 0; t < 4; t++) acc[i][t] = (f32x4){0.f, 0.f, 0.f, 0.f};

    const unsigned short* xTb = xT + (((size_t)b) << 10) * (size_t)Cin;
    const int* idxb = (b >= 128 ? idxB : idxA) + (size_t)(b & 127) * 3069;

    float na = 1.0f, nc = 0.0f;
    if (NORM) {
        float2 st = stats_from(normSums, b, normCount);
        na = st.y; nc = -st.x * st.y;
    }

    // --- staging mapping ---
    const int gr = tid >> 1, gh = tid & 1;       // gt row (n), 32-elem half
    int s0, s1, s2;
    {
        int n = nt0 + gr;
        int t0 = (n == 0) ? 0 : (n - 1);         // n==0 row is garbage, zeroed later
        s0 = idxb[3 * t0]; s1 = idxb[3 * t0 + 1]; s2 = idxb[3 * t0 + 2];
    }
    const int wr   = (BM == 128) ? (tid >> 1) : (tid >> 2);  // wt row (o)
    const int wseg = (BM == 128) ? (tid & 1) : (tid & 3);    // segment of NW packets
    const unsigned short* wrow = wq + (size_t)(o0 + wr) * K + wseg * (NW * 8);
    const int gswz = gr & 7, wswz = wr & 7;

    uint4 g0, g1, g2, g3, w0, w1, w2, w3;

#define LOADC(KC) {                                                              \
        const int k64_ = (KC) << 6;                                              \
        const int j_   = k64_ >> cinShift;                                       \
        const int c0_  = k64_ & (Cin - 1);                                       \
        const int src_ = (j_ == 0) ? s0 : ((j_ == 1) ? s1 : s2);                 \
        const uint4* gp_ = (const uint4*)(xTb + (size_t)src_ * Cin + c0_ + gh * 32); \
        g0 = gp_[0]; g1 = gp_[1]; g2 = gp_[2]; g3 = gp_[3];                      \
        const uint4* wp_ = (const uint4*)(wrow + k64_);                          \
        w0 = wp_[0]; w1 = wp_[1];                                                \
        if (NW == 4) { w2 = wp_[2]; w3 = wp_[3]; }                               \
    }

#define STAGE() {                                                                \
        uint4 h0 = g0, h1 = g1, h2 = g2, h3 = g3;                                \
        if (NORM) {                                                              \
            h0 = norm8(h0, na, nc); h1 = norm8(h1, na, nc);                      \
            h2 = norm8(h2, na, nc); h3 = norm8(h3, na, nc);                      \
        }                                                                        \
        *(uint4*)&gt[gr * 64 + (((gh << 2) | 0) ^ gswz) * 8] = h0;               \
        *(uint4*)&gt[gr * 64 + (((gh << 2) | 1) ^ gswz) * 8] = h1;               \
        *(uint4*)&gt[gr * 64 + (((gh << 2) | 2) ^ gswz) * 8] = h2;               \
        *(uint4*)&gt[gr * 64 + (((gh << 2) | 3) ^ gswz) * 8] = h3;               \
        *(uint4*)&wt[wr * 64 + ((wseg * NW + 0) ^ wswz) * 8] = w0;               \
        *(uint4*)&wt[wr * 64 + ((wseg * NW + 1) ^ wswz) * 8] = w1;               \
        if (NW == 4) {                                                           \
            *(uint4*)&wt[wr * 64 + ((wseg * NW + 2) ^ wswz) * 8] = w2;           \
            *(uint4*)&wt[wr * 64 + ((wseg * NW + 3) ^ wswz) * 8] = w3;           \
        }                                                                        \
    }

    const int nChunks = K >> 6;
    LOADC(0);
    for (int kc = 0; kc < nChunks; ++kc) {
        if (kc) __syncthreads();        // prior chunk's readers done
        STAGE();                        // waits in-flight loads, writes LDS
        if (kc + 1 < nChunks) LOADC(kc + 1);  // prefetch stays in flight past barrier
        __syncthreads();                // staged data visible
#pragma unroll
        for (int st = 0; st < 2; ++st) {
            short8 af[MT], bfv[4];
            const int qb = st * 4 + quad;
#pragma unroll
            for (int i = 0; i < MT; i++) {
                const int orow = wo * WM + i * 16 + l15;
                af[i] = *(const short8*)&wt[orow * 64 + ((qb ^ blkid) << 3)];
            }
#pragma unroll
            for (int t = 0; t < 4; t++) {
                const int nrow = wn * 64 + t * 16 + l15;
                bfv[t] = *(const short8*)&gt[nrow * 64 + ((qb ^ blkid) << 3)];
            }
#pragma unroll
            for (int i = 0; i < MT; i++)
#pragma unroll
                for (int t = 0; t < 4; t++)
                    acc[i][t] = __builtin_amdgcn_mfma_f32_16x16x32_bf16(
                        af[i], bfv[t], acc[i][t], 0, 0, 0);
        }
    }
#undef LOADC
#undef STAGE

    // epilogue: bias, zero col 0, store (unless POOL), fused stats, fused max-pool
    float lsum = 0.f, lsq = 0.f;
#pragma unroll
    for (int i = 0; i < MT; i++) {
        const int ob = o0 + wo * WM + i * 16 + quad * 4;
        const float4 bv = *(const float4*)(bias + ob);
        float mx0 = -1e30f, mx1 = -1e30f, mx2 = -1e30f, mx3 = -1e30f;
#pragma unroll
        for (int t = 0; t < 4; t++) {
            const int n = nt0 + wn * 64 + t * 16 + l15;
            float v0 = acc[i][t][0] + bv.x;
            float v1 = acc[i][t][1] + bv.y;
            float v2 = acc[i][t][2] + bv.z;
            float v3 = acc[i][t][3] + bv.w;
            if (n == 0) { v0 = v1 = v2 = v3 = 0.f; }
            lsum += v0 + v1 + v2 + v3;
            lsq  += v0 * v0 + v1 * v1 + v2 * v2 + v3 * v3;
            if (POOL) {
                mx0 = fmaxf(mx0, v0); mx1 = fmaxf(mx1, v1);
                mx2 = fmaxf(mx2, v2); mx3 = fmaxf(mx3, v3);
            } else {
                uint2 pk;
                pk.x = pack_bf16_pair(v0, v1);
                pk.y = pack_bf16_pair(v2, v3);
                *(uint2*)&out[((size_t)b * 1024 + n) * O + ob] = pk;
            }
        }
        if (POOL) {
#pragma unroll
            for (int off = 1; off < 16; off <<= 1) {
                mx0 = fmaxf(mx0, __shfl_xor(mx0, off));
                mx1 = fmaxf(mx1, __shfl_xor(mx1, off));
                mx2 = fmaxf(mx2, __shfl_xor(mx2, off));
                mx3 = fmaxf(mx3, __shfl_xor(mx3, off));
            }
            if (l15 == 0) {
                atomicMaxF(&pmax[(size_t)b * 64 + ob + 0], mx0);
                atomicMaxF(&pmax[(size_t)b * 64 + ob + 1], mx1);
                atomicMaxF(&pmax[(size_t)b * 64 + ob + 2], mx2);
                atomicMaxF(&pmax[(size_t)b * 64 + ob + 3], mx3);
            }
        }
    }
#pragma unroll
    for (int off = 32; off > 0; off >>= 1) {
        lsum += __shfl_down(lsum, off);
        lsq  += __shfl_down(lsq, off);
    }
    float* red = (float*)wt;  // wt dead after K-loop
    if (lane == 0) { red[wave] = lsum; red[4 + wave] = lsq; }
    __syncthreads();
    if (tid == 0) {
        atomicAdd(&sums[2 * b + 0], red[0] + red[1] + red[2] + red[3]);
        atomicAdd(&sums[2 * b + 1], red[4] + red[5] + red[6] + red[7]);
    }
}

// pooled max -> normalize -> fc1+lrelu -> fc2
__global__ __launch_bounds__(64) void fc_head(
    const float* __restrict__ pmax, const float* __restrict__ sums3, float count,
    const float* __restrict__ w_fc1, const float* __restrict__ b_fc1,
    const float* __restrict__ w_fc2, const float* __restrict__ b_fc2,
    float* __restrict__ y)
{
    const int b = blockIdx.x, t = threadIdx.x;
    __shared__ float pooled[64];
    __shared__ float hid[32];
    float2 s = stats_from(sums3, b, count);
    pooled[t] = (pmax[(size_t)b * 64 + t] - s.x) * s.y;
    __syncthreads();
    if (t < 32) {
        float h = b_fc1[t];
#pragma unroll
        for (int c = 0; c < 64; c++) h += pooled[c] * w_fc1[t * 64 + c];
        hid[t] = LRELU(h);
    }
    __syncthreads();
    if (t == 0) {
        float v = b_fc2[0];
#pragma unroll
        for (int c = 0; c < 32; c++) v += hid[c] * w_fc2[c];
        y[b] = v;
    }
}

__global__ void sigmoid_diff(const float* __restrict__ y1,
                             const float* __restrict__ y2,
                             float* __restrict__ out)
{
    int b = threadIdx.x;
    if (b < 128) out[b] = 1.0f / (1.0f + expf(-(y1[b] - y2[b])));
}

extern "C" void kernel_launch(void* const* d_in, const int* in_sizes, int n_in,
                              void* d_out, int out_size, void* d_ws, size_t ws_size,
                              hipStream_t stream)
{
    const float* data1 = (const float*)d_in[0];
    const int*   idx1  = (const int*)d_in[1];
    const float* data2 = (const float*)d_in[2];
    const int*   idx2  = (const int*)d_in[3];
    const float* w1 = (const float*)d_in[4];
    const float* b1 = (const float*)d_in[5];
    const float* w2 = (const float*)d_in[6];
    const float* b2 = (const float*)d_in[7];
    const float* w3 = (const float*)d_in[8];
    const float* b3 = (const float*)d_in[9];
    const float* wfc1 = (const float*)d_in[10];
    const float* bfc1 = (const float*)d_in[11];
    const float* wfc2 = (const float*)d_in[12];
    const float* bfc2 = (const float*)d_in[13];

    const size_t needM = (size_t)256 * 1024 * (64 + 256 + 128) * 2 + 768 * 1024;
    const bool merged = ws_size >= needM;
    const int nB = merged ? 256 : 128;
    const size_t szXT = (size_t)nB * 1024 * 64 * 2;
    const size_t szA1 = (size_t)nB * 1024 * 256 * 2;
    const size_t szA2 = (size_t)nB * 1024 * 128 * 2;

    char* ws = (char*)d_ws;
    unsigned short* xT = (unsigned short*)ws;
    unsigned short* a1 = (unsigned short*)(ws + szXT);
    unsigned short* a2 = (unsigned short*)(ws + szXT + szA1);
    char* tail = ws + szXT + szA1 + szA2;
    unsigned short* wq1 = (unsigned short*)tail;                 // 96 KB
    unsigned short* wq2 = (unsigned short*)(tail + 128 * 1024);  // 192 KB
    unsigned short* wq3 = (unsigned short*)(tail + 384 * 1024);  // 48 KB
    float* sums = (float*)(tail + 448 * 1024);                   // 3*nB*2 f32
    float* pmax = (float*)(tail + 512 * 1024);                   // nB*64 f32
    float* yv   = (float*)(tail + 640 * 1024);                   // 256 f32

    prep_weights<<<96, 256, 0, stream>>>(w1, wq1, 256, 64);
    prep_weights<<<96, 256, 0, stream>>>(w2, wq2, 128, 256);
    prep_weights<<<96, 256, 0, stream>>>(w3, wq3, 64, 128);

    const int nIter = merged ? 1 : 2;
    for (int t = 0; t < nIter; ++t) {
        const float* dA = (merged || t == 0) ? data1 : data2;
        const float* dB = merged ? data2 : dA;
        const int* iA = (merged || t == 0) ? idx1 : idx2;
        const int* iB = merged ? idx2 : iA;
        float* s1 = sums;
        float* s2 = sums + nB * 2;
        float* s3 = sums + nB * 4;

        hipMemsetAsync(sums, 0, 3 * (size_t)nB * 2 * sizeof(float), stream);
        hipMemsetAsync(pmax, 0xFF, (size_t)nB * 64 * sizeof(float), stream);

        transpose_in<<<dim3(16, nB), 256, 0, stream>>>(dA, dB, xT);

        conv_mfma<128, false, false><<<dim3(nB, 2, 8), 256, 0, stream>>>(
            xT, iA, iB, wq1, b1, a1, s1, nullptr, nullptr, 0.0f, 64, 6, 256, 192);

        conv_mfma<128, false, true><<<dim3(nB, 1, 8), 256, 0, stream>>>(
            a1, iA, iB, wq2, b2, a2, s2, nullptr, s1, 256.0f * 1024.0f, 256, 8, 128, 768);

        conv_mfma<64, true, true><<<dim3(nB, 1, 8), 256, 0, stream>>>(
            a2, iA, iB, wq3, b3, nullptr, s3, pmax, s2, 128.0f * 1024.0f, 128, 7, 64, 384);

        fc_head<<<nB, 64, 0, stream>>>(pmax, s3, 64.0f * 1024.0f,
                                       wfc1, bfc1, wfc2, bfc2,
                                       yv + (merged ? 0 : t * 128));
    }
    sigmoid_diff<<<1, 128, 0, stream>>>(yv, yv + 128, (float*)d_out);
}

// Round 11
// 344.342 us; speedup vs baseline: 1.4985x; 1.0090x over previous
//
#include <hip/hip_runtime.h>
#include <math.h>

typedef __attribute__((ext_vector_type(8))) short short8;
typedef __attribute__((ext_vector_type(4))) float f32x4;
typedef __attribute__((ext_vector_type(2))) float f32x2;

#define LRELU(x) ((x) > 0.0f ? (x) : 0.01f * (x))

__device__ __forceinline__ float bf2f(unsigned short h) {
    return __uint_as_float(((unsigned int)h) << 16);
}
__device__ __forceinline__ unsigned short f2bf(float f) {
    unsigned int u = __float_as_uint(f);
    return (unsigned short)((u + 0x7FFFu + ((u >> 16) & 1u)) >> 16);
}
// round-half-up bf16 pair pack: ~5 VALU vs ~10 for RNE; <=0.5 ULP error
__device__ __forceinline__ unsigned int pack_bf16_pair(float lo, float hi) {
    unsigned int ul = __float_as_uint(lo) + 0x8000u;
    unsigned int uh = __float_as_uint(hi) + 0x8000u;
    return (ul >> 16) | (uh & 0xFFFF0000u);
}
__device__ __forceinline__ float2 stats_from(const float* sums, int b, float count) {
    float s = sums[2 * b], q = sums[2 * b + 1];
    float mean = s / count;
    float var = (q - s * s / count) / (count - 1.0f);  // ddof=1
    var = fmaxf(var, 0.0f);
    return make_float2(mean, 1.0f / (sqrtf(var) + 1e-5f));
}
// init pattern 0xFFFFFFFF (-NaN): positives via signed max, negatives via unsigned min
__device__ __forceinline__ void atomicMaxF(float* a, float v) {
    if (v >= 0.0f) atomicMax((int*)a, __float_as_int(v));
    else           atomicMin((unsigned int*)a, __float_as_uint(v));
}
// y = lrelu(x * a + c) on a packed bf16 pair, via packed-f32 (VOP3P) ops
__device__ __forceinline__ unsigned int norm_pair(unsigned int u, float a, float c) {
    f32x2 v;
    v.x = __uint_as_float(u << 16);          // lo bf16 -> f32
    v.y = __uint_as_float(u & 0xFFFF0000u);  // hi bf16 -> f32
    v = v * a + c;                           // v_pk_fma_f32
    f32x2 m = v * 0.01f;                     // v_pk_mul_f32
    v = __builtin_elementwise_max(v, m);     // v_pk_max_f32
    return pack_bf16_pair(v.x, v.y);
}
__device__ __forceinline__ uint4 norm8(uint4 v, float a, float c) {
    v.x = norm_pair(v.x, a, c); v.y = norm_pair(v.y, a, c);
    v.z = norm_pair(v.z, a, c); v.w = norm_pair(v.w, a, c);
    return v;
}

// MFMA fragment block: LDS -> frags -> 2 k-stages of 16x16x32 bf16 MFMAs
template <int MT, int WM>
__device__ __forceinline__ void mfma_step(const unsigned short* wt, const unsigned short* gt,
                                          f32x4 (&acc)[MT][4],
                                          int wo, int wn, int quad, int l15, int blkid)
{
#pragma unroll
    for (int st = 0; st < 2; ++st) {
        short8 af[MT], bfv[4];
        const int qb = st * 4 + quad;
#pragma unroll
        for (int i = 0; i < MT; i++) {
            const int orow = wo * WM + i * 16 + l15;
            af[i] = *(const short8*)&wt[orow * 64 + ((qb ^ blkid) << 3)];
        }
#pragma unroll
        for (int t = 0; t < 4; t++) {
            const int nrow = wn * 64 + t * 16 + l15;
            bfv[t] = *(const short8*)&gt[nrow * 64 + ((qb ^ blkid) << 3)];
        }
#pragma unroll
        for (int i = 0; i < MT; i++)
#pragma unroll
            for (int t = 0; t < 4; t++)
                acc[i][t] = __builtin_amdgcn_mfma_f32_16x16x32_bf16(
                    af[i], bfv[t], acc[i][t], 0, 0, 0);
    }
}

// w [O][Cin][3] f32  ->  wq [O][3*Cin] bf16 with k' = j*Cin + c
__global__ void prep_weights(const float* __restrict__ w, unsigned short* __restrict__ wq,
                             int O, int Cin)
{
    const int K = 3 * Cin, total = O * K;
    for (int i = blockIdx.x * blockDim.x + threadIdx.x; i < total;
         i += gridDim.x * blockDim.x) {
        int o = i / K, kp = i - o * K;
        int j = kp / Cin, c = kp - j * Cin;
        wq[i] = f2bf(w[(o * Cin + c) * 3 + j]);
    }
}

// data [128][64][1024] f32 -> xT [nB][1024][64] bf16 (tower select on b>=128)
__global__ __launch_bounds__(256) void transpose_in(const float* __restrict__ inA,
                                                    const float* __restrict__ inB,
                                                    unsigned short* __restrict__ xT)
{
    const int b = blockIdx.y, n0 = blockIdx.x * 64;
    const float* in = (b >= 128 ? inB : inA) + ((size_t)(b & 127) * 64) * 1024;
    const int tid = threadIdx.x;
    __shared__ float tile[64][65];
    const int nn = tid & 63, cw = tid >> 6;
#pragma unroll
    for (int i = 0; i < 16; i++) {
        int c = i * 4 + cw;
        tile[c][nn] = in[(size_t)c * 1024 + n0 + nn];
    }
    __syncthreads();
    const int n = tid >> 2, cp = (tid & 3) * 16;
    unsigned int pk[8];
#pragma unroll
    for (int i = 0; i < 8; i++) {
        unsigned short lo = f2bf(tile[cp + 2 * i][n]);
        unsigned short hi = f2bf(tile[cp + 2 * i + 1][n]);
        pk[i] = (unsigned int)lo | ((unsigned int)hi << 16);
    }
    unsigned short* dst = xT + ((size_t)b * 1024 + n0 + n) * 64 + cp;
    uint4 v0 = {pk[0], pk[1], pk[2], pk[3]};
    uint4 v1 = {pk[4], pk[5], pk[6], pk[7]};
    *(uint4*)dst = v0;
    *(uint4*)(dst + 8) = v1;
}

// MFMA gather-conv. Register-staged K-loop, software-pipelined 2 chunks deep
// (sets A/B of NAMED scalar uint4 -- arrays fail SROA -> scratch, the R5-R7 bug).
// Each load set is issued ~2 chunk-periods before its use, covering the ~900-cyc
// random-gather latency that made R10 latency-bound (4200 cyc/chunk vs 840 MFMA).
// __launch_bounds__(256, 2) EXACTLY: (256,4) makes the allocator target 64 VGPR and
// spill the staging scalars (R9: 430 MB scratch traffic). Do not raise.
template <int BM, bool POOL, bool NORM>
__global__ __launch_bounds__(256, 2) void conv_mfma(
    const unsigned short* __restrict__ xT,   // [nB][1024][Cin] bf16 (raw, pre-norm)
    const int* __restrict__ idxA,            // [128][3069]
    const int* __restrict__ idxB,
    const unsigned short* __restrict__ wq,   // [O][K] bf16 (k'=j*Cin+c)
    const float* __restrict__ bias,          // [O] f32
    unsigned short* __restrict__ out,        // [nB][1024][O] bf16 (unused if POOL)
    float* __restrict__ sums,                // [nB][2] accum (this layer's raw stats)
    float* __restrict__ pmax,                // [nB][64] (POOL only)
    const float* __restrict__ normSums,      // [nB][2] prev-layer stats (NORM only)
    float normCount, int Cin, int cinShift, int O, int K)
{
    constexpr int WM = BM / 2, MT = WM / 16;
    constexpr int NW = (BM == 128) ? 4 : 2;      // 16B packets of wt per thread
    const int b   = blockIdx.x;
    const int o0  = blockIdx.y * BM;
    const int nt0 = blockIdx.z << 7;
    const int tid = threadIdx.x;
    const int lane = tid & 63, wave = tid >> 6;
    const int wo = wave & 1, wn = wave >> 1;
    const int quad = lane >> 4, l15 = lane & 15;
    const int blkid = lane & 7;

    __shared__ __align__(16) unsigned short wt[BM * 64];
    __shared__ __align__(16) unsigned short gt[128 * 64];

    f32x4 acc[MT][4];
#pragma unroll
    for (int i = 0; i < MT; i++)
#pragma unroll
        for (int t = 0; t < 4; t++) acc[i][t] = (f32x4){0.f, 0.f, 0.f, 0.f};

    const unsigned short* xTb = xT + (((size_t)b) << 10) * (size_t)Cin;
    const int* idxb = (b >= 128 ? idxB : idxA) + (size_t)(b & 127) * 3069;

    float na = 1.0f, nc = 0.0f;
    if (NORM) {
        float2 st = stats_from(normSums, b, normCount);
        na = st.y; nc = -st.x * st.y;
    }

    // --- staging mapping ---
    const int gr = tid >> 1, gh = tid & 1;       // gt row (n), 32-elem half
    int s0, s1, s2;
    {
        int n = nt0 + gr;
        int t0 = (n == 0) ? 0 : (n - 1);         // n==0 row is garbage, zeroed later
        s0 = idxb[3 * t0]; s1 = idxb[3 * t0 + 1]; s2 = idxb[3 * t0 + 2];
    }
    const int wr   = (BM == 128) ? (tid >> 1) : (tid >> 2);  // wt row (o)
    const int wseg = (BM == 128) ? (tid & 1) : (tid & 3);    // segment of NW packets
    const unsigned short* wrow = wq + (size_t)(o0 + wr) * K + wseg * (NW * 8);
    const int gswz = gr & 7, wswz = wr & 7;

    // two independent staging sets (pipeline depth 2), all named scalars
    uint4 g0A, g1A, g2A, g3A, w0A, w1A, w2A, w3A;
    uint4 g0B, g1B, g2B, g3B, w0B, w1B, w2B, w3B;

#define LOADC(S, KC) {                                                           \
        const int k64_ = (KC) << 6;                                              \
        const int j_   = k64_ >> cinShift;                                       \
        const int c0_  = k64_ & (Cin - 1);                                       \
        const int src_ = (j_ == 0) ? s0 : ((j_ == 1) ? s1 : s2);                 \
        const uint4* gp_ = (const uint4*)(xTb + (size_t)src_ * Cin + c0_ + gh * 32); \
        g0##S = gp_[0]; g1##S = gp_[1]; g2##S = gp_[2]; g3##S = gp_[3];          \
        const uint4* wp_ = (const uint4*)(wrow + k64_);                          \
        w0##S = wp_[0]; w1##S = wp_[1];                                          \
        if (NW == 4) { w2##S = wp_[2]; w3##S = wp_[3]; }                         \
    }

#define STAGE(S) {                                                               \
        uint4 h0 = g0##S, h1 = g1##S, h2 = g2##S, h3 = g3##S;                    \
        if (NORM) {                                                              \
            h0 = norm8(h0, na, nc); h1 = norm8(h1, na, nc);                      \
            h2 = norm8(h2, na, nc); h3 = norm8(h3, na, nc);                      \
        }                                                                        \
        *(uint4*)&gt[gr * 64 + (((gh << 2) | 0) ^ gswz) * 8] = h0;               \
        *(uint4*)&gt[gr * 64 + (((gh << 2) | 1) ^ gswz) * 8] = h1;               \
        *(uint4*)&gt[gr * 64 + (((gh << 2) | 2) ^ gswz) * 8] = h2;               \
        *(uint4*)&gt[gr * 64 + (((gh << 2) | 3) ^ gswz) * 8] = h3;               \
        *(uint4*)&wt[wr * 64 + ((wseg * NW + 0) ^ wswz) * 8] = w0##S;            \
        *(uint4*)&wt[wr * 64 + ((wseg * NW + 1) ^ wswz) * 8] = w1##S;            \
        if (NW == 4) {                                                           \
            *(uint4*)&wt[wr * 64 + ((wseg * NW + 2) ^ wswz) * 8] = w2##S;        \
            *(uint4*)&wt[wr * 64 + ((wseg * NW + 3) ^ wswz) * 8] = w3##S;        \
        }                                                                        \
    }

    const int nChunks = K >> 6;      // conv1:3, conv2:12, conv3:6
    LOADC(A, 0);
    if (nChunks > 1) LOADC(B, 1);
    int kc = 0;
    for (; kc + 2 <= nChunks; kc += 2) {
        if (kc) __syncthreads();              // prior chunk's LDS readers done
        STAGE(A);                             // waits set-A loads only (older vmcnt)
        if (kc + 2 < nChunks) LOADC(A, kc + 2);   // refill A: consumed 2 chunks later
        __syncthreads();
        mfma_step<MT, WM>(wt, gt, acc, wo, wn, quad, l15, blkid);
        __syncthreads();
        STAGE(B);
        if (kc + 3 < nChunks) LOADC(B, kc + 3);
        __syncthreads();
        mfma_step<MT, WM>(wt, gt, acc, wo, wn, quad, l15, blkid);
    }
    if (kc < nChunks) {                       // odd tail (conv1: chunk 2 in set A)
        __syncthreads();
        STAGE(A);
        __syncthreads();
        mfma_step<MT, WM>(wt, gt, acc, wo, wn, quad, l15, blkid);
    }
#undef LOADC
#undef STAGE

    // epilogue: bias, zero col 0, store (unless POOL), fused stats, fused max-pool
    float lsum = 0.f, lsq = 0.f;
#pragma unroll
    for (int i = 0; i < MT; i++) {
        const int ob = o0 + wo * WM + i * 16 + quad * 4;
        const float4 bv = *(const float4*)(bias + ob);
        float mx0 = -1e30f, mx1 = -1e30f, mx2 = -1e30f, mx3 = -1e30f;
#pragma unroll
        for (int t = 0; t < 4; t++) {
            const int n = nt0 + wn * 64 + t * 16 + l15;
            float v0 = acc[i][t][0] + bv.x;
            float v1 = acc[i][t][1] + bv.y;
            float v2 = acc[i][t][2] + bv.z;
            float v3 = acc[i][t][3] + bv.w;
            if (n == 0) { v0 = v1 = v2 = v3 = 0.f; }
            lsum += v0 + v1 + v2 + v3;
            lsq  += v0 * v0 + v1 * v1 + v2 * v2 + v3 * v3;
            if (POOL) {
                mx0 = fmaxf(mx0, v0); mx1 = fmaxf(mx1, v1);
                mx2 = fmaxf(mx2, v2); mx3 = fmaxf(mx3, v3);
            } else {
                uint2 pk;
                pk.x = pack_bf16_pair(v0, v1);
                pk.y = pack_bf16_pair(v2, v3);
                *(uint2*)&out[((size_t)b * 1024 + n) * O + ob] = pk;
            }
        }
        if (POOL) {
#pragma unroll
            for (int off = 1; off < 16; off <<= 1) {
                mx0 = fmaxf(mx0, __shfl_xor(mx0, off));
                mx1 = fmaxf(mx1, __shfl_xor(mx1, off));
                mx2 = fmaxf(mx2, __shfl_xor(mx2, off));
                mx3 = fmaxf(mx3, __shfl_xor(mx3, off));
            }
            if (l15 == 0) {
                atomicMaxF(&pmax[(size_t)b * 64 + ob + 0], mx0);
                atomicMaxF(&pmax[(size_t)b * 64 + ob + 1], mx1);
                atomicMaxF(&pmax[(size_t)b * 64 + ob + 2], mx2);
                atomicMaxF(&pmax[(size_t)b * 64 + ob + 3], mx3);
            }
        }
    }
#pragma unroll
    for (int off = 32; off > 0; off >>= 1) {
        lsum += __shfl_down(lsum, off);
        lsq  += __shfl_down(lsq, off);
    }
    float* red = (float*)wt;  // wt dead after K-loop
    if (lane == 0) { red[wave] = lsum; red[4 + wave] = lsq; }
    __syncthreads();
    if (tid == 0) {
        atomicAdd(&sums[2 * b + 0], red[0] + red[1] + red[2] + red[3]);
        atomicAdd(&sums[2 * b + 1], red[4] + red[5] + red[6] + red[7]);
    }
}

// pooled max -> normalize -> fc1+lrelu -> fc2
__global__ __launch_bounds__(64) void fc_head(
    const float* __restrict__ pmax, const float* __restrict__ sums3, float count,
    const float* __restrict__ w_fc1, const float* __restrict__ b_fc1,
    const float* __restrict__ w_fc2, const float* __restrict__ b_fc2,
    float* __restrict__ y)
{
    const int b = blockIdx.x, t = threadIdx.x;
    __shared__ float pooled[64];
    __shared__ float hid[32];
    float2 s = stats_from(sums3, b, count);
    pooled[t] = (pmax[(size_t)b * 64 + t] - s.x) * s.y;
    __syncthreads();
    if (t < 32) {
        float h = b_fc1[t];
#pragma unroll
        for (int c = 0; c < 64; c++) h += pooled[c] * w_fc1[t * 64 + c];
        hid[t] = LRELU(h);
    }
    __syncthreads();
    if (t == 0) {
        float v = b_fc2[0];
#pragma unroll
        for (int c = 0; c < 32; c++) v += hid[c] * w_fc2[c];
        y[b] = v;
    }
}

__global__ void sigmoid_diff(const float* __restrict__ y1,
                             const float* __restrict__ y2,
                             float* __restrict__ out)
{
    int b = threadIdx.x;
    if (b < 128) out[b] = 1.0f / (1.0f + expf(-(y1[b] - y2[b])));
}

extern "C" void kernel_launch(void* const* d_in, const int* in_sizes, int n_in,
                              void* d_out, int out_size, void* d_ws, size_t ws_size,
                              hipStream_t stream)
{
    const float* data1 = (const float*)d_in[0];
    const int*   idx1  = (const int*)d_in[1];
    const float* data2 = (const float*)d_in[2];
    const int*   idx2  = (const int*)d_in[3];
    const float* w1 = (const float*)d_in[4];
    const float* b1 = (const float*)d_in[5];
    const float* w2 = (const float*)d_in[6];
    const float* b2 = (const float*)d_in[7];
    const float* w3 = (const float*)d_in[8];
    const float* b3 = (const float*)d_in[9];
    const float* wfc1 = (const float*)d_in[10];
    const float* bfc1 = (const float*)d_in[11];
    const float* wfc2 = (const float*)d_in[12];
    const float* bfc2 = (const float*)d_in[13];

    const size_t needM = (size_t)256 * 1024 * (64 + 256 + 128) * 2 + 768 * 1024;
    const bool merged = ws_size >= needM;
    const int nB = merged ? 256 : 128;
    const size_t szXT = (size_t)nB * 1024 * 64 * 2;
    const size_t szA1 = (size_t)nB * 1024 * 256 * 2;
    const size_t szA2 = (size_t)nB * 1024 * 128 * 2;

    char* ws = (char*)d_ws;
    unsigned short* xT = (unsigned short*)ws;
    unsigned short* a1 = (unsigned short*)(ws + szXT);
    unsigned short* a2 = (unsigned short*)(ws + szXT + szA1);
    char* tail = ws + szXT + szA1 + szA2;
    unsigned short* wq1 = (unsigned short*)tail;                 // 96 KB
    unsigned short* wq2 = (unsigned short*)(tail + 128 * 1024);  // 192 KB
    unsigned short* wq3 = (unsigned short*)(tail + 384 * 1024);  // 48 KB
    float* sums = (float*)(tail + 448 * 1024);                   // 3*nB*2 f32
    float* pmax = (float*)(tail + 512 * 1024);                   // nB*64 f32
    float* yv   = (float*)(tail + 640 * 1024);                   // 256 f32

    prep_weights<<<96, 256, 0, stream>>>(w1, wq1, 256, 64);
    prep_weights<<<96, 256, 0, stream>>>(w2, wq2, 128, 256);
    prep_weights<<<96, 256, 0, stream>>>(w3, wq3, 64, 128);

    const int nIter = merged ? 1 : 2;
    for (int t = 0; t < nIter; ++t) {
        const float* dA = (merged || t == 0) ? data1 : data2;
        const float* dB = merged ? data2 : dA;
        const int* iA = (merged || t == 0) ? idx1 : idx2;
        const int* iB = merged ? idx2 : iA;
        float* s1 = sums;
        float* s2 = sums + nB * 2;
        float* s3 = sums + nB * 4;

        hipMemsetAsync(sums, 0, 3 * (size_t)nB * 2 * sizeof(float), stream);
        hipMemsetAsync(pmax, 0xFF, (size_t)nB * 64 * sizeof(float), stream);

        transpose_in<<<dim3(16, nB), 256, 0, stream>>>(dA, dB, xT);

        conv_mfma<128, false, false><<<dim3(nB, 2, 8), 256, 0, stream>>>(
            xT, iA, iB, wq1, b1, a1, s1, nullptr, nullptr, 0.0f, 64, 6, 256, 192);

        conv_mfma<128, false, true><<<dim3(nB, 1, 8), 256, 0, stream>>>(
            a1, iA, iB, wq2, b2, a2, s2, nullptr, s1, 256.0f * 1024.0f, 256, 8, 128, 768);

        conv_mfma<64, true, true><<<dim3(nB, 1, 8), 256, 0, stream>>>(
            a2, iA, iB, wq3, b3, nullptr, s3, pmax, s2, 128.0f * 1024.0f, 128, 7, 64, 384);

        fc_head<<<nB, 64, 0, stream>>>(pmax, s3, 64.0f * 1024.0f,
                                       wfc1, bfc1, wfc2, bfc2,
                                       yv + (merged ? 0 : t * 128));
    }
    sigmoid_diff<<<1, 128, 0, stream>>>(yv, yv + 128, (float*)d_out);
}

// Round 12
// 328.619 us; speedup vs baseline: 1.5702x; 1.0478x over previous
//
#include <hip/hip_runtime.h>
#include <math.h>

typedef __attribute__((ext_vector_type(8))) short short8;
typedef __attribute__((ext_vector_type(4))) float f32x4;
typedef __attribute__((ext_vector_type(2))) float f32x2;

#define LRELU(x) ((x) > 0.0f ? (x) : 0.01f * (x))

__device__ __forceinline__ float bf2f(unsigned short h) {
    return __uint_as_float(((unsigned int)h) << 16);
}
__device__ __forceinline__ unsigned short f2bf(float f) {
    unsigned int u = __float_as_uint(f);
    return (unsigned short)((u + 0x7FFFu + ((u >> 16) & 1u)) >> 16);
}
// round-half-up bf16 pair pack: ~5 VALU vs ~10 for RNE; <=0.5 ULP error
__device__ __forceinline__ unsigned int pack_bf16_pair(float lo, float hi) {
    unsigned int ul = __float_as_uint(lo) + 0x8000u;
    unsigned int uh = __float_as_uint(hi) + 0x8000u;
    return (ul >> 16) | (uh & 0xFFFF0000u);
}
__device__ __forceinline__ float2 stats_from(const float* sums, int b, float count) {
    float s = sums[2 * b], q = sums[2 * b + 1];
    float mean = s / count;
    float var = (q - s * s / count) / (count - 1.0f);  // ddof=1
    var = fmaxf(var, 0.0f);
    return make_float2(mean, 1.0f / (sqrtf(var) + 1e-5f));
}
// init pattern 0xFFFFFFFF (-NaN): positives via signed max, negatives via unsigned min
__device__ __forceinline__ void atomicMaxF(float* a, float v) {
    if (v >= 0.0f) atomicMax((int*)a, __float_as_int(v));
    else           atomicMin((unsigned int*)a, __float_as_uint(v));
}
// y = lrelu(x * a + c) on a packed bf16 pair, via packed-f32 (VOP3P) ops
__device__ __forceinline__ unsigned int norm_pair(unsigned int u, float a, float c) {
    f32x2 v;
    v.x = __uint_as_float(u << 16);
    v.y = __uint_as_float(u & 0xFFFF0000u);
    v = v * a + c;
    f32x2 m = v * 0.01f;
    v = __builtin_elementwise_max(v, m);
    return pack_bf16_pair(v.x, v.y);
}
__device__ __forceinline__ uint4 norm8(uint4 v, float a, float c) {
    v.x = norm_pair(v.x, a, c); v.y = norm_pair(v.y, a, c);
    v.z = norm_pair(v.z, a, c); v.w = norm_pair(v.w, a, c);
    return v;
}
// 4 fp8 e4m3 (one uint) -> lrelu(x*a+c) -> 4 bf16 (uint2). HW cvt replaces the
// bf16 unpack shifts, so VALU cost matches the bf16 norm path.
__device__ __forceinline__ uint2 fp8x4_nl(unsigned int u, float a, float c) {
    f32x2 lo = __builtin_amdgcn_cvt_pk_f32_fp8(u, false);
    f32x2 hi = __builtin_amdgcn_cvt_pk_f32_fp8(u, true);
    lo = lo * a + c; hi = hi * a + c;
    f32x2 ml = lo * 0.01f, mh = hi * 0.01f;
    lo = __builtin_elementwise_max(lo, ml);
    hi = __builtin_elementwise_max(hi, mh);
    uint2 r;
    r.x = pack_bf16_pair(lo.x, lo.y);
    r.y = pack_bf16_pair(hi.x, hi.y);
    return r;
}

// MFMA fragment block: LDS -> frags -> 2 k-stages of 16x16x32 bf16 MFMAs
template <int MT, int WM>
__device__ __forceinline__ void mfma_step(const unsigned short* wt, const unsigned short* gt,
                                          f32x4 (&acc)[MT][4],
                                          int wo, int wn, int quad, int l15, int blkid)
{
#pragma unroll
    for (int st = 0; st < 2; ++st) {
        short8 af[MT], bfv[4];
        const int qb = st * 4 + quad;
#pragma unroll
        for (int i = 0; i < MT; i++) {
            const int orow = wo * WM + i * 16 + l15;
            af[i] = *(const short8*)&wt[orow * 64 + ((qb ^ blkid) << 3)];
        }
#pragma unroll
        for (int t = 0; t < 4; t++) {
            const int nrow = wn * 64 + t * 16 + l15;
            bfv[t] = *(const short8*)&gt[nrow * 64 + ((qb ^ blkid) << 3)];
        }
#pragma unroll
        for (int i = 0; i < MT; i++)
#pragma unroll
            for (int t = 0; t < 4; t++)
                acc[i][t] = __builtin_amdgcn_mfma_f32_16x16x32_bf16(
                    af[i], bfv[t], acc[i][t], 0, 0, 0);
    }
}

// w [O][Cin][3] f32  ->  wq [O][3*Cin] bf16 with k' = j*Cin + c
__global__ void prep_weights(const float* __restrict__ w, unsigned short* __restrict__ wq,
                             int O, int Cin)
{
    const int K = 3 * Cin, total = O * K;
    for (int i = blockIdx.x * blockDim.x + threadIdx.x; i < total;
         i += gridDim.x * blockDim.x) {
        int o = i / K, kp = i - o * K;
        int j = kp / Cin, c = kp - j * Cin;
        wq[i] = f2bf(w[(o * Cin + c) * 3 + j]);
    }
}

// data [128][64][1024] f32 -> xT [nB][1024][64] bf16 (tower select on b>=128)
__global__ __launch_bounds__(256) void transpose_in(const float* __restrict__ inA,
                                                    const float* __restrict__ inB,
                                                    unsigned short* __restrict__ xT)
{
    const int b = blockIdx.y, n0 = blockIdx.x * 64;
    const float* in = (b >= 128 ? inB : inA) + ((size_t)(b & 127) * 64) * 1024;
    const int tid = threadIdx.x;
    __shared__ float tile[64][65];
    const int nn = tid & 63, cw = tid >> 6;
#pragma unroll
    for (int i = 0; i < 16; i++) {
        int c = i * 4 + cw;
        tile[c][nn] = in[(size_t)c * 1024 + n0 + nn];
    }
    __syncthreads();
    const int n = tid >> 2, cp = (tid & 3) * 16;
    unsigned int pk[8];
#pragma unroll
    for (int i = 0; i < 8; i++) {
        unsigned short lo = f2bf(tile[cp + 2 * i][n]);
        unsigned short hi = f2bf(tile[cp + 2 * i + 1][n]);
        pk[i] = (unsigned int)lo | ((unsigned int)hi << 16);
    }
    unsigned short* dst = xT + ((size_t)b * 1024 + n0 + n) * 64 + cp;
    uint4 v0 = {pk[0], pk[1], pk[2], pk[3]};
    uint4 v1 = {pk[4], pk[5], pk[6], pk[7]};
    *(uint4*)dst = v0;
    *(uint4*)(dst + 8) = v1;
}

// MFMA gather-conv, register-staged 2-deep pipelined K-loop (named scalars only:
// local arrays fail SROA -> scratch, the R5-R7 600MB bug).
// FP8IN:  gathered tensor is fp8 e4m3; decode fused into the norm step.
// FP8OUT: epilogue stores fp8 e4m3 via v_cvt_pk_fp8_f32 (halves streaming writes).
// R11 diagnosis: conv2 is random-access-HBM-bound (~2.2 TB/s on 128B granules,
// FETCH = 1x compulsory pass of a1) -> bytes are the lever, hence fp8 a1.
// __launch_bounds__(256, 2) EXACTLY: (256,4) spills staging (R9). Do not raise.
template <int BM, bool POOL, bool NORM, bool FP8IN, bool FP8OUT>
__global__ __launch_bounds__(256, 2) void conv_mfma(
    const void* __restrict__ xTv,            // [nB][1024][Cin] bf16 or fp8 (raw)
    const int* __restrict__ idxA,            // [128][3069]
    const int* __restrict__ idxB,
    const unsigned short* __restrict__ wq,   // [O][K] bf16 (k'=j*Cin+c)
    const float* __restrict__ bias,          // [O] f32
    void* __restrict__ out,                  // [nB][1024][O] bf16/fp8 (unused if POOL)
    float* __restrict__ sums,                // [nB][2] accum (this layer's raw stats)
    float* __restrict__ pmax,                // [nB][64] (POOL only)
    const float* __restrict__ normSums,      // [nB][2] prev-layer stats (NORM only)
    float normCount, int Cin, int cinShift, int O, int K)
{
    constexpr int WM = BM / 2, MT = WM / 16;
    constexpr int NW = (BM == 128) ? 4 : 2;      // 16B packets of wt per thread
    const int b   = blockIdx.x;
    const int o0  = blockIdx.y * BM;
    const int nt0 = blockIdx.z << 7;
    const int tid = threadIdx.x;
    const int lane = tid & 63, wave = tid >> 6;
    const int wo = wave & 1, wn = wave >> 1;
    const int quad = lane >> 4, l15 = lane & 15;
    const int blkid = lane & 7;

    __shared__ __align__(16) unsigned short wt[BM * 64];
    __shared__ __align__(16) unsigned short gt[128 * 64];

    f32x4 acc[MT][4];
#pragma unroll
    for (int i = 0; i < MT; i++)
#pragma unroll
        for (int t = 0; t < 4; t++) acc[i][t] = (f32x4){0.f, 0.f, 0.f, 0.f};

    const unsigned short* xTb16 = (const unsigned short*)xTv + (((size_t)b) << 10) * (size_t)Cin;
    const unsigned char*  xTb8  = (const unsigned char*)xTv  + (((size_t)b) << 10) * (size_t)Cin;
    const int* idxb = (b >= 128 ? idxB : idxA) + (size_t)(b & 127) * 3069;

    float na = 1.0f, nc = 0.0f;
    if (NORM) {
        float2 st = stats_from(normSums, b, normCount);
        na = st.y; nc = -st.x * st.y;
    }

    // --- staging mapping ---
    const int gr = tid >> 1, gh = tid & 1;       // gt row (n), 32-channel half
    int s0, s1, s2;
    {
        int n = nt0 + gr;
        int t0 = (n == 0) ? 0 : (n - 1);         // n==0 row is garbage, zeroed later
        s0 = idxb[3 * t0]; s1 = idxb[3 * t0 + 1]; s2 = idxb[3 * t0 + 2];
    }
    const int wr   = (BM == 128) ? (tid >> 1) : (tid >> 2);  // wt row (o)
    const int wseg = (BM == 128) ? (tid & 1) : (tid & 3);    // segment of NW packets
    const unsigned short* wrow = wq + (size_t)(o0 + wr) * K + wseg * (NW * 8);
    const int gswz = gr & 7, wswz = wr & 7;

    // two independent staging sets (pipeline depth 2), all named scalars
    uint4 g0A, g1A, g2A, g3A, w0A, w1A, w2A, w3A;
    uint4 g0B, g1B, g2B, g3B, w0B, w1B, w2B, w3B;

#define LOADC(S, KC) {                                                           \
        const int k64_ = (KC) << 6;                                              \
        const int j_   = k64_ >> cinShift;                                       \
        const int c0_  = k64_ & (Cin - 1);                                       \
        const int src_ = (j_ == 0) ? s0 : ((j_ == 1) ? s1 : s2);                 \
        if (FP8IN) {                                                             \
            const uint4* gp_ = (const uint4*)(xTb8 + (size_t)src_ * Cin + c0_ + gh * 32); \
            g0##S = gp_[0]; g1##S = gp_[1];                                      \
        } else {                                                                 \
            const uint4* gp_ = (const uint4*)(xTb16 + (size_t)src_ * Cin + c0_ + gh * 32); \
            g0##S = gp_[0]; g1##S = gp_[1]; g2##S = gp_[2]; g3##S = gp_[3];      \
        }                                                                        \
        const uint4* wp_ = (const uint4*)(wrow + k64_);                          \
        w0##S = wp_[0]; w1##S = wp_[1];                                          \
        if (NW == 4) { w2##S = wp_[2]; w3##S = wp_[3]; }                         \
    }

#define STAGE(S) {                                                               \
        uint4 h0, h1, h2, h3;                                                    \
        if (FP8IN) {                                                             \
            uint2 p0 = fp8x4_nl(g0##S.x, na, nc), p1 = fp8x4_nl(g0##S.y, na, nc);\
            uint2 p2 = fp8x4_nl(g0##S.z, na, nc), p3 = fp8x4_nl(g0##S.w, na, nc);\
            h0.x = p0.x; h0.y = p0.y; h0.z = p1.x; h0.w = p1.y;                  \
            h1.x = p2.x; h1.y = p2.y; h1.z = p3.x; h1.w = p3.y;                  \
            p0 = fp8x4_nl(g1##S.x, na, nc); p1 = fp8x4_nl(g1##S.y, na, nc);      \
            p2 = fp8x4_nl(g1##S.z, na, nc); p3 = fp8x4_nl(g1##S.w, na, nc);      \
            h2.x = p0.x; h2.y = p0.y; h2.z = p1.x; h2.w = p1.y;                  \
            h3.x = p2.x; h3.y = p2.y; h3.z = p3.x; h3.w = p3.y;                  \
        } else {                                                                 \
            h0 = g0##S; h1 = g1##S; h2 = g2##S; h3 = g3##S;                      \
            if (NORM) {                                                          \
                h0 = norm8(h0, na, nc); h1 = norm8(h1, na, nc);                  \
                h2 = norm8(h2, na, nc); h3 = norm8(h3, na, nc);                  \
            }                                                                    \
        }                                                                        \
        *(uint4*)&gt[gr * 64 + (((gh << 2) | 0) ^ gswz) * 8] = h0;               \
        *(uint4*)&gt[gr * 64 + (((gh << 2) | 1) ^ gswz) * 8] = h1;               \
        *(uint4*)&gt[gr * 64 + (((gh << 2) | 2) ^ gswz) * 8] = h2;               \
        *(uint4*)&gt[gr * 64 + (((gh << 2) | 3) ^ gswz) * 8] = h3;               \
        *(uint4*)&wt[wr * 64 + ((wseg * NW + 0) ^ wswz) * 8] = w0##S;            \
        *(uint4*)&wt[wr * 64 + ((wseg * NW + 1) ^ wswz) * 8] = w1##S;            \
        if (NW == 4) {                                                           \
            *(uint4*)&wt[wr * 64 + ((wseg * NW + 2) ^ wswz) * 8] = w2##S;        \
            *(uint4*)&wt[wr * 64 + ((wseg * NW + 3) ^ wswz) * 8] = w3##S;        \
        }                                                                        \
    }

    const int nChunks = K >> 6;      // conv1:3, conv2:12, conv3:6
    LOADC(A, 0);
    if (nChunks > 1) LOADC(B, 1);
    int kc = 0;
    for (; kc + 2 <= nChunks; kc += 2) {
        if (kc) __syncthreads();              // prior chunk's LDS readers done
        STAGE(A);                             // waits set-A loads only
        if (kc + 2 < nChunks) LOADC(A, kc + 2);
        __syncthreads();
        mfma_step<MT, WM>(wt, gt, acc, wo, wn, quad, l15, blkid);
        __syncthreads();
        STAGE(B);
        if (kc + 3 < nChunks) LOADC(B, kc + 3);
        __syncthreads();
        mfma_step<MT, WM>(wt, gt, acc, wo, wn, quad, l15, blkid);
    }
    if (kc < nChunks) {                       // odd tail (conv1: chunk 2 in set A)
        __syncthreads();
        STAGE(A);
        __syncthreads();
        mfma_step<MT, WM>(wt, gt, acc, wo, wn, quad, l15, blkid);
    }
#undef LOADC
#undef STAGE

    // epilogue: bias, zero col 0, store (unless POOL), fused stats, fused max-pool
    float lsum = 0.f, lsq = 0.f;
#pragma unroll
    for (int i = 0; i < MT; i++) {
        const int ob = o0 + wo * WM + i * 16 + quad * 4;
        const float4 bv = *(const float4*)(bias + ob);
        float mx0 = -1e30f, mx1 = -1e30f, mx2 = -1e30f, mx3 = -1e30f;
#pragma unroll
        for (int t = 0; t < 4; t++) {
            const int n = nt0 + wn * 64 + t * 16 + l15;
            float v0 = acc[i][t][0] + bv.x;
            float v1 = acc[i][t][1] + bv.y;
            float v2 = acc[i][t][2] + bv.z;
            float v3 = acc[i][t][3] + bv.w;
            if (n == 0) { v0 = v1 = v2 = v3 = 0.f; }
            lsum += v0 + v1 + v2 + v3;
            lsq  += v0 * v0 + v1 * v1 + v2 * v2 + v3 * v3;
            if (POOL) {
                mx0 = fmaxf(mx0, v0); mx1 = fmaxf(mx1, v1);
                mx2 = fmaxf(mx2, v2); mx3 = fmaxf(mx3, v3);
            } else if (FP8OUT) {
                int r = __builtin_amdgcn_cvt_pk_fp8_f32(v0, v1, 0, false);
                r = __builtin_amdgcn_cvt_pk_fp8_f32(v2, v3, r, true);
                *(unsigned int*)&((unsigned char*)out)[((size_t)b * 1024 + n) * O + ob] =
                    (unsigned int)r;
            } else {
                uint2 pk;
                pk.x = pack_bf16_pair(v0, v1);
                pk.y = pack_bf16_pair(v2, v3);
                *(uint2*)&((unsigned short*)out)[((size_t)b * 1024 + n) * O + ob] = pk;
            }
        }
        if (POOL) {
#pragma unroll
            for (int off = 1; off < 16; off <<= 1) {
                mx0 = fmaxf(mx0, __shfl_xor(mx0, off));
                mx1 = fmaxf(mx1, __shfl_xor(mx1, off));
                mx2 = fmaxf(mx2, __shfl_xor(mx2, off));
                mx3 = fmaxf(mx3, __shfl_xor(mx3, off));
            }
            if (l15 == 0) {
                atomicMaxF(&pmax[(size_t)b * 64 + ob + 0], mx0);
                atomicMaxF(&pmax[(size_t)b * 64 + ob + 1], mx1);
                atomicMaxF(&pmax[(size_t)b * 64 + ob + 2], mx2);
                atomicMaxF(&pmax[(size_t)b * 64 + ob + 3], mx3);
            }
        }
    }
#pragma unroll
    for (int off = 32; off > 0; off >>= 1) {
        lsum += __shfl_down(lsum, off);
        lsq  += __shfl_down(lsq, off);
    }
    float* red = (float*)wt;  // wt dead after K-loop
    if (lane == 0) { red[wave] = lsum; red[4 + wave] = lsq; }
    __syncthreads();
    if (tid == 0) {
        atomicAdd(&sums[2 * b + 0], red[0] + red[1] + red[2] + red[3]);
        atomicAdd(&sums[2 * b + 1], red[4] + red[5] + red[6] + red[7]);
    }
}

// pooled max -> normalize -> fc1+lrelu -> fc2
__global__ __launch_bounds__(64) void fc_head(
    const float* __restrict__ pmax, const float* __restrict__ sums3, float count,
    const float* __restrict__ w_fc1, const float* __restrict__ b_fc1,
    const float* __restrict__ w_fc2, const float* __restrict__ b_fc2,
    float* __restrict__ y)
{
    const int b = blockIdx.x, t = threadIdx.x;
    __shared__ float pooled[64];
    __shared__ float hid[32];
    float2 s = stats_from(sums3, b, count);
    pooled[t] = (pmax[(size_t)b * 64 + t] - s.x) * s.y;
    __syncthreads();
    if (t < 32) {
        float h = b_fc1[t];
#pragma unroll
        for (int c = 0; c < 64; c++) h += pooled[c] * w_fc1[t * 64 + c];
        hid[t] = LRELU(h);
    }
    __syncthreads();
    if (t == 0) {
        float v = b_fc2[0];
#pragma unroll
        for (int c = 0; c < 32; c++) v += hid[c] * w_fc2[c];
        y[b] = v;
    }
}

__global__ void sigmoid_diff(const float* __restrict__ y1,
                             const float* __restrict__ y2,
                             float* __restrict__ out)
{
    int b = threadIdx.x;
    if (b < 128) out[b] = 1.0f / (1.0f + expf(-(y1[b] - y2[b])));
}

extern "C" void kernel_launch(void* const* d_in, const int* in_sizes, int n_in,
                              void* d_out, int out_size, void* d_ws, size_t ws_size,
                              hipStream_t stream)
{
    const float* data1 = (const float*)d_in[0];
    const int*   idx1  = (const int*)d_in[1];
    const float* data2 = (const float*)d_in[2];
    const int*   idx2  = (const int*)d_in[3];
    const float* w1 = (const float*)d_in[4];
    const float* b1 = (const float*)d_in[5];
    const float* w2 = (const float*)d_in[6];
    const float* b2 = (const float*)d_in[7];
    const float* w3 = (const float*)d_in[8];
    const float* b3 = (const float*)d_in[9];
    const float* wfc1 = (const float*)d_in[10];
    const float* bfc1 = (const float*)d_in[11];
    const float* wfc2 = (const float*)d_in[12];
    const float* bfc2 = (const float*)d_in[13];

    // a1 is fp8 (1B/elem); xT and a2 stay bf16
    const size_t needM = (size_t)256 * 1024 * (64 * 2 + 256 * 1 + 128 * 2) + 768 * 1024;
    const bool merged = ws_size >= needM;
    const int nB = merged ? 256 : 128;
    const size_t szXT = (size_t)nB * 1024 * 64 * 2;
    const size_t szA1 = (size_t)nB * 1024 * 256;       // fp8
    const size_t szA2 = (size_t)nB * 1024 * 128 * 2;

    char* ws = (char*)d_ws;
    unsigned short* xT = (unsigned short*)ws;
    unsigned char*  a1 = (unsigned char*)(ws + szXT);
    unsigned short* a2 = (unsigned short*)(ws + szXT + szA1);
    char* tail = ws + szXT + szA1 + szA2;
    unsigned short* wq1 = (unsigned short*)tail;                 // 96 KB
    unsigned short* wq2 = (unsigned short*)(tail + 128 * 1024);  // 192 KB
    unsigned short* wq3 = (unsigned short*)(tail + 384 * 1024);  // 48 KB
    float* sums = (float*)(tail + 448 * 1024);                   // 3*nB*2 f32
    float* pmax = (float*)(tail + 512 * 1024);                   // nB*64 f32
    float* yv   = (float*)(tail + 640 * 1024);                   // 256 f32

    prep_weights<<<96, 256, 0, stream>>>(w1, wq1, 256, 64);
    prep_weights<<<96, 256, 0, stream>>>(w2, wq2, 128, 256);
    prep_weights<<<96, 256, 0, stream>>>(w3, wq3, 64, 128);

    const int nIter = merged ? 1 : 2;
    for (int t = 0; t < nIter; ++t) {
        const float* dA = (merged || t == 0) ? data1 : data2;
        const float* dB = merged ? data2 : dA;
        const int* iA = (merged || t == 0) ? idx1 : idx2;
        const int* iB = merged ? idx2 : iA;
        float* s1 = sums;
        float* s2 = sums + nB * 2;
        float* s3 = sums + nB * 4;

        hipMemsetAsync(sums, 0, 3 * (size_t)nB * 2 * sizeof(float), stream);
        hipMemsetAsync(pmax, 0xFF, (size_t)nB * 64 * sizeof(float), stream);

        transpose_in<<<dim3(16, nB), 256, 0, stream>>>(dA, dB, xT);

        // conv1: bf16 in, fp8 out (halves the 134MB streaming write)
        conv_mfma<128, false, false, false, true><<<dim3(nB, 2, 8), 256, 0, stream>>>(
            xT, iA, iB, wq1, b1, a1, s1, nullptr, nullptr, 0.0f, 64, 6, 256, 192);

        // conv2: fp8 in (halves the random-gather HBM read), bf16 out
        conv_mfma<128, false, true, true, false><<<dim3(nB, 1, 8), 256, 0, stream>>>(
            a1, iA, iB, wq2, b2, a2, s2, nullptr, s1, 256.0f * 1024.0f, 256, 8, 128, 768);

        conv_mfma<64, true, true, false, false><<<dim3(nB, 1, 8), 256, 0, stream>>>(
            a2, iA, iB, wq3, b3, nullptr, s3, pmax, s2, 128.0f * 1024.0f, 128, 7, 64, 384);

        fc_head<<<nB, 64, 0, stream>>>(pmax, s3, 64.0f * 1024.0f,
                                       wfc1, bfc1, wfc2, bfc2,
                                       yv + (merged ? 0 : t * 128));
    }
    sigmoid_diff<<<1, 128, 0, stream>>>(yv, yv + 128, (float*)d_out);
}